// Round 1
// baseline (241.680 us; speedup 1.0000x reference)
//
#include <hip/hip_runtime.h>
#include <stdint.h>
#include <math.h>

#define NUM_ANCHORS 5
#define NUM_CLASSES 80
#define MAX_BOXES   50

// Workspace layout (uint32 words):
//   ws[0] : float   sum of p over masked cells
//   ws[1] : uint32  count of distinct masked cells (== list length)
//   ws[2] : int32   max p as float bits (init 0xFF800000 = -inf)
//   ws[3] : uint32  done-block counter (last-block finalize)
//   ws[4 .. 4+nB*MAX_BOXES) : int32 list of flat cell ids
//
// No dedup bitmap: flat encodes the batch index, so duplicates can only
// occur among one batch's 50 boxes, which sit in a single wave -> dedup
// in-register via __shfl. This removes the init_ws kernel entirely.

// ONE block: init header words, then build the deduped cell list.
// 16 waves x (nB/16) batches; lane = box index within batch.
__global__ void __launch_bounds__(1024)
build_list(const float* __restrict__ target,
           uint32_t* __restrict__ ws,
           int nB, int nH, int nW) {
#pragma clang fp contract(off)
    int tid = threadIdx.x;
    if (tid < 4) ws[tid] = (tid == 2) ? 0xFF800000u : 0u;
    __syncthreads();

    int lane  = tid & 63;
    int wave  = tid >> 6;
    int nWav  = blockDim.x >> 6;
    int* list = (int*)(ws + 4);

    for (int b = wave; b < nB; b += nWav) {
        const float* t = target + (long)b * MAX_BOXES * 5;
        float x = 1.0f, y = 0.0f, w = 0.0f, h = 0.0f;
        if (lane < MAX_BOXES) {
            x = t[lane * 5 + 1];
            y = t[lane * 5 + 2];
            w = t[lane * 5 + 3];
            h = t[lane * 5 + 4];
        }
        // valid = cumprod(x != 0): lanes strictly before the first zero box
        unsigned long long zb = __ballot(lane < MAX_BOXES && x == 0.0f);
        int first_zero = zb ? (__ffsll(zb) - 1) : MAX_BOXES;
        bool valid = lane < first_zero;   // implies lane < MAX_BOXES

        float gx = x * (float)nW;
        float gy = y * (float)nH;
        float gw = w * (float)nW;
        float gh = h * (float)nH;
        int gi = min(max((int)floorf(gx), 0), nW - 1);
        int gj = min(max((int)floorf(gy), 0), nH - 1);

        const float aw[NUM_ANCHORS] = {0.57273f, 1.87446f, 3.33843f, 7.88282f, 9.77052f};
        const float ah[NUM_ANCHORS] = {0.677385f, 2.06253f, 5.47434f, 3.52778f, 9.16828f};
        int best = 0; float bestiou = -1.0f;
        #pragma unroll
        for (int n = 0; n < NUM_ANCHORS; ++n) {
            float inter = fminf(gw, aw[n]) * fminf(gh, ah[n]);
            float uni   = gw * gh + aw[n] * ah[n] - inter;
            float iou   = inter / uni;
            if (iou > bestiou) { bestiou = iou; best = n; }  // first-max-wins
        }
        int flat = ((b * NUM_ANCHORS + best) * nH + gj) * nW + gi;

        // in-wave dedup: keep only the first occurrence among valid lanes
        unsigned long long vmask = __ballot(valid);
        bool dup = false;
        for (int j = 0; j < MAX_BOXES; ++j) {
            int fj = __shfl(flat, j, 64);
            dup |= (j < lane) && (((vmask >> j) & 1ull) != 0) && (fj == flat);
        }
        if (valid && !dup) {
            int idx = (int)atomicAdd(&ws[1], 1u);   // wave-coalesced by compiler
            list[idx] = flat;
        }
    }
}

// One wave per list entry: 80-class softmax, block-combined atomics,
// last-done-block writes the final output (no separate finalize launch).
__global__ void __launch_bounds__(256)
reduce_list(const float* __restrict__ output,
            uint32_t* __restrict__ ws,
            const int* __restrict__ reqd,
            float* __restrict__ out,
            int HW) {
    __shared__ float sp[4];
    __shared__ float sm[4];
    float*    sumf    = (float*)ws;          // ws[0]
    int*      maxbits = (int*)(ws + 2);      // ws[2]
    uint32_t* done    = ws + 3;              // ws[3]
    const int* list   = (const int*)(ws + 4);

    int lane = threadIdx.x & 63;
    int wave = threadIdx.x >> 6;
    int g = blockIdx.x * 4 + wave;
    int count = (int)ws[1];
    float p = 0.0f, pm = -INFINITY;
    if (g < count) {
        int cell = list[g];
        int ba = cell / HW;          // b*NUM_ANCHORS + a
        int hw = cell - ba * HW;     // gj*nW + gi
        const float* ptr = output + ((long)(ba * (5 + NUM_CLASSES) + 5)) * HW + hw;
        float v0 = ptr[(long)lane * HW];
        float v1 = (lane < NUM_CLASSES - 64) ? ptr[(long)(lane + 64) * HW] : -INFINITY;
        float mx = fmaxf(v0, v1);
        #pragma unroll
        for (int off = 32; off; off >>= 1) mx = fmaxf(mx, __shfl_xor(mx, off, 64));
        float e0 = expf(v0 - mx);
        float e1 = (lane < NUM_CLASSES - 64) ? expf(v1 - mx) : 0.0f;
        float s = e0 + e1;
        #pragma unroll
        for (int off = 32; off; off >>= 1) s += __shfl_xor(s, off, 64);
        int rq = *reqd;
        float lr = (rq < 64) ? __shfl(v0, rq, 64) : __shfl(v1, rq - 64, 64);
        p = expf(lr - mx) / s;
        pm = p;
    }
    if (lane == 0) { sp[wave] = p; sm[wave] = pm; }
    __syncthreads();
    if (threadIdx.x == 0) {
        float ts = 0.0f, tm = -INFINITY;
        #pragma unroll
        for (int w = 0; w < 4; ++w) { ts += sp[w]; tm = fmaxf(tm, sm[w]); }
        if (tm > -INFINITY) {
            atomicAdd(sumf, ts);
            atomicMax(maxbits, __float_as_int(tm));  // p > 0: int order == float order
        }
        __threadfence();                              // order our atomics before done++
        uint32_t old = atomicAdd(done, 1u);
        if (old == (uint32_t)gridDim.x - 1u) {
            // all other blocks' atomics are ordered before their done++;
            // read back via device-scope atomics.
            float ts2 = atomicAdd(sumf, 0.0f);
            int   tm2 = atomicMax(maxbits, (int)0x80000000);  // INT_MIN: no-op read
            out[0] = ts2 / (float)count;
            out[1] = __int_as_float(tm2);
        }
    }
}

extern "C" void kernel_launch(void* const* d_in, const int* in_sizes, int n_in,
                              void* d_out, int out_size, void* d_ws, size_t ws_size,
                              hipStream_t stream) {
    const float* output = (const float*)d_in[0];
    const float* target = (const float*)d_in[1];
    const int*   reqd   = (const int*)d_in[2];
    float* out = (float*)d_out;

    int nB = in_sizes[1] / (MAX_BOXES * 5);                           // 64
    int HW = in_sizes[0] / (nB * (5 + NUM_CLASSES) * NUM_ANCHORS);    // 1444
    int nW = 1; while (nW * nW < HW) ++nW;                            // 38
    int nH = HW / nW;                                                 // 38

    uint32_t* ws = (uint32_t*)d_ws;

    build_list<<<1, 1024, 0, stream>>>(target, ws, nB, nH, nW);

    int listCap = nB * MAX_BOXES;                                     // 3200
    int rblocks = (listCap + 3) / 4;  // 4 waves (entries) per 256-thread block
    reduce_list<<<rblocks, 256, 0, stream>>>(output, ws, reqd, out, HW);
}

// Round 3
// 231.061 us; speedup vs baseline: 1.0460x; 1.0460x over previous
//
#include <hip/hip_runtime.h>
#include <stdint.h>
#include <math.h>

#define NUM_ANCHORS 5
#define NUM_CLASSES 80
#define MAX_BOXES   50

// Workspace layout (uint32 words):
//   ws[0] : float   sum of p over masked cells
//   ws[1] : uint32  count of distinct masked cells (== list length)
//   ws[2] : int32   max p as float bits (init 0xFF800000 = -inf)
//   ws[3] : pad
//   ws[4 .. 4+nB*MAX_BOXES) : int32 list of flat cell ids
//
// No dedup bitmap: flat encodes the batch index, so duplicates can only
// occur among one batch's 50 boxes, which sit in a single wave -> dedup
// in-register via __shfl.  Header init is folded into build_list.
// Finalize stays a separate 1-thread kernel: the last-block-done pattern
// (800x __threadfence + same-address atomics) cost ~26 us on gfx950
// because device-scope fences force cross-XCD L2 ordering traffic
// (round-1 regression, 215 -> 241 us).

// ONE block: init header words, then build the deduped cell list.
// 16 waves x (nB/16) batches; lane = box index within batch.
__global__ void __launch_bounds__(1024)
build_list(const float* __restrict__ target,
           uint32_t* __restrict__ ws,
           int nB, int nH, int nW) {
#pragma clang fp contract(off)
    int tid = threadIdx.x;
    if (tid < 4) ws[tid] = (tid == 2) ? 0xFF800000u : 0u;
    __syncthreads();

    int lane  = tid & 63;
    int wave  = tid >> 6;
    int nWav  = blockDim.x >> 6;
    int* list = (int*)(ws + 4);

    for (int b = wave; b < nB; b += nWav) {
        const float* t = target + (long)b * MAX_BOXES * 5;
        float x = 1.0f, y = 0.0f, w = 0.0f, h = 0.0f;
        if (lane < MAX_BOXES) {
            x = t[lane * 5 + 1];
            y = t[lane * 5 + 2];
            w = t[lane * 5 + 3];
            h = t[lane * 5 + 4];
        }
        // valid = cumprod(x != 0): lanes strictly before the first zero box
        unsigned long long zb = __ballot(lane < MAX_BOXES && x == 0.0f);
        int first_zero = zb ? (__ffsll(zb) - 1) : MAX_BOXES;
        bool valid = lane < first_zero;   // implies lane < MAX_BOXES

        float gx = x * (float)nW;
        float gy = y * (float)nH;
        float gw = w * (float)nW;
        float gh = h * (float)nH;
        int gi = min(max((int)floorf(gx), 0), nW - 1);
        int gj = min(max((int)floorf(gy), 0), nH - 1);

        const float aw[NUM_ANCHORS] = {0.57273f, 1.87446f, 3.33843f, 7.88282f, 9.77052f};
        const float ah[NUM_ANCHORS] = {0.677385f, 2.06253f, 5.47434f, 3.52778f, 9.16828f};
        int best = 0; float bestiou = -1.0f;
        #pragma unroll
        for (int n = 0; n < NUM_ANCHORS; ++n) {
            float inter = fminf(gw, aw[n]) * fminf(gh, ah[n]);
            float uni   = gw * gh + aw[n] * ah[n] - inter;
            float iou   = inter / uni;
            if (iou > bestiou) { bestiou = iou; best = n; }  // first-max-wins
        }
        int flat = ((b * NUM_ANCHORS + best) * nH + gj) * nW + gi;

        // in-wave dedup: keep only the first occurrence among valid lanes
        unsigned long long vmask = __ballot(valid);
        bool dup = false;
        for (int j = 0; j < MAX_BOXES; ++j) {
            int fj = __shfl(flat, j, 64);
            dup |= (j < lane) && (((vmask >> j) & 1ull) != 0) && (fj == flat);
        }
        if (valid && !dup) {
            int idx = (int)atomicAdd(&ws[1], 1u);
            list[idx] = flat;
        }
    }
}

// One wave per list entry: 80-class softmax, block-combined atomics.
// No done-counter / no __threadfence (see header comment).
__global__ void __launch_bounds__(256)
reduce_list(const float* __restrict__ output,
            uint32_t* __restrict__ ws,
            const int* __restrict__ reqd,
            int HW) {
    __shared__ float sp[4];
    __shared__ float sm[4];
    float*    sumf    = (float*)ws;          // ws[0]
    int*      maxbits = (int*)(ws + 2);      // ws[2]
    const int* list   = (const int*)(ws + 4);

    int lane = threadIdx.x & 63;
    int wave = threadIdx.x >> 6;
    int g = blockIdx.x * 4 + wave;
    int count = (int)ws[1];
    float p = 0.0f, pm = -INFINITY;
    if (g < count) {
        int cell = list[g];
        int ba = cell / HW;          // b*NUM_ANCHORS + a
        int hw = cell - ba * HW;     // gj*nW + gi
        const float* ptr = output + ((long)(ba * (5 + NUM_CLASSES) + 5)) * HW + hw;
        float v0 = ptr[(long)lane * HW];
        float v1 = (lane < NUM_CLASSES - 64) ? ptr[(long)(lane + 64) * HW] : -INFINITY;
        float mx = fmaxf(v0, v1);
        #pragma unroll
        for (int off = 32; off; off >>= 1) mx = fmaxf(mx, __shfl_xor(mx, off, 64));
        float e0 = expf(v0 - mx);
        float e1 = (lane < NUM_CLASSES - 64) ? expf(v1 - mx) : 0.0f;
        float s = e0 + e1;
        #pragma unroll
        for (int off = 32; off; off >>= 1) s += __shfl_xor(s, off, 64);
        int rq = *reqd;
        float lr = (rq < 64) ? __shfl(v0, rq, 64) : __shfl(v1, rq - 64, 64);
        p = expf(lr - mx) / s;
        pm = p;
    }
    if (lane == 0) { sp[wave] = p; sm[wave] = pm; }
    __syncthreads();
    if (threadIdx.x == 0) {
        float ts = 0.0f, tm = -INFINITY;
        #pragma unroll
        for (int w = 0; w < 4; ++w) { ts += sp[w]; tm = fmaxf(tm, sm[w]); }
        if (tm > -INFINITY) {
            atomicAdd(sumf, ts);
            atomicMax(maxbits, __float_as_int(tm));  // p > 0: int order == float order
        }
    }
}

__global__ void finalize(const uint32_t* __restrict__ ws,
                         float* __restrict__ out) {
    const float* sumf = (const float*)ws;
    const int*   maxb = (const int*)(ws + 2);
    out[0] = sumf[0] / (float)ws[1];
    out[1] = __int_as_float(maxb[0]);
}

extern "C" void kernel_launch(void* const* d_in, const int* in_sizes, int n_in,
                              void* d_out, int out_size, void* d_ws, size_t ws_size,
                              hipStream_t stream) {
    const float* output = (const float*)d_in[0];
    const float* target = (const float*)d_in[1];
    const int*   reqd   = (const int*)d_in[2];
    float* out = (float*)d_out;

    int nB = in_sizes[1] / (MAX_BOXES * 5);                           // 64
    int HW = in_sizes[0] / (nB * (5 + NUM_CLASSES) * NUM_ANCHORS);    // 1444
    int nW = 1; while (nW * nW < HW) ++nW;                            // 38
    int nH = HW / nW;                                                 // 38

    uint32_t* ws = (uint32_t*)d_ws;

    build_list<<<1, 1024, 0, stream>>>(target, ws, nB, nH, nW);

    int listCap = nB * MAX_BOXES;                                     // 3200
    int rblocks = (listCap + 3) / 4;  // 4 waves (entries) per 256-thread block
    reduce_list<<<rblocks, 256, 0, stream>>>(output, ws, reqd, HW);

    finalize<<<1, 1, 0, stream>>>(ws, out);
}

// Round 4
// 200.802 us; speedup vs baseline: 1.2036x; 1.1507x over previous
//
#include <hip/hip_runtime.h>
#include <stdint.h>
#include <math.h>

#define NUM_ANCHORS 5
#define NUM_CLASSES 80
#define MAX_BOXES   50

// Workspace layout (uint32 words) — NOTHING requires pre-initialization;
// every word that is read was unconditionally written earlier in the same
// iteration (kills init_ws AND all device-scope atomics; round-1/3
// post-mortems: 800x threadfence+atomics cost ~10us, single-block
// build_list cost ~16us on gfx950):
//   cnt  = ws[0 .. nB)                     int   deduped-box count per batch
//   list = ws[nB .. nB+nB*50)              int   flat cell ids, slot b*50+rank
//   psum = ws[.. +rblocks)                 float per-reduce-block partial sum
//   pmax = ws[.. +rblocks)                 float per-reduce-block partial max

// One wave per batch: dedup via __shfl (duplicates can only occur within a
// batch's 50 boxes, and flat encodes b), write to rank-indexed fixed slots.
__global__ void __launch_bounds__(64)
build_list(const float* __restrict__ target,
           int* __restrict__ cnt,
           int* __restrict__ list,
           int nH, int nW) {
#pragma clang fp contract(off)
    int b = blockIdx.x;
    int lane = threadIdx.x;
    const float* t = target + (long)b * MAX_BOXES * 5;
    float x = 1.0f, y = 0.0f, w = 0.0f, h = 0.0f;
    if (lane < MAX_BOXES) {
        x = t[lane * 5 + 1];
        y = t[lane * 5 + 2];
        w = t[lane * 5 + 3];
        h = t[lane * 5 + 4];
    }
    // valid = cumprod(x != 0): lanes strictly before the first zero box
    unsigned long long zb = __ballot(lane < MAX_BOXES && x == 0.0f);
    int first_zero = zb ? (__ffsll(zb) - 1) : MAX_BOXES;
    bool valid = lane < first_zero;   // implies lane < MAX_BOXES

    float gx = x * (float)nW;
    float gy = y * (float)nH;
    float gw = w * (float)nW;
    float gh = h * (float)nH;
    int gi = min(max((int)floorf(gx), 0), nW - 1);
    int gj = min(max((int)floorf(gy), 0), nH - 1);

    const float aw[NUM_ANCHORS] = {0.57273f, 1.87446f, 3.33843f, 7.88282f, 9.77052f};
    const float ah[NUM_ANCHORS] = {0.677385f, 2.06253f, 5.47434f, 3.52778f, 9.16828f};
    int best = 0; float bestiou = -1.0f;
    #pragma unroll
    for (int n = 0; n < NUM_ANCHORS; ++n) {
        float inter = fminf(gw, aw[n]) * fminf(gh, ah[n]);
        float uni   = gw * gh + aw[n] * ah[n] - inter;
        float iou   = inter / uni;
        if (iou > bestiou) { bestiou = iou; best = n; }  // first-max-wins
    }
    int flat = ((b * NUM_ANCHORS + best) * nH + gj) * nW + gi;

    // in-wave dedup: keep only the first occurrence among valid lanes
    unsigned long long vmask = __ballot(valid);
    bool dup = false;
    for (int j = 0; j < MAX_BOXES; ++j) {
        int fj = __shfl(flat, j, 64);
        dup |= (j < lane) && (((vmask >> j) & 1ull) != 0) && (fj == flat);
    }
    bool keep = valid && !dup;
    unsigned long long kmask = __ballot(keep);
    if (keep) {
        int rank = __popcll(kmask & ((1ull << lane) - 1ull));
        list[b * MAX_BOXES + rank] = flat;
    }
    if (lane == 0) cnt[b] = (int)__popcll(kmask);
}

// One wave per (batch, slot): 80-class softmax; per-block partials written
// unconditionally (no atomics, no pre-init required).
__global__ void __launch_bounds__(256)
reduce_list(const float* __restrict__ output,
            const int* __restrict__ cnt,
            const int* __restrict__ list,
            float* __restrict__ psum,
            float* __restrict__ pmax,
            const int* __restrict__ reqd,
            int HW, int total) {
    __shared__ float sp[4];
    __shared__ float sm[4];
    int lane = threadIdx.x & 63;
    int wave = threadIdx.x >> 6;
    int g = blockIdx.x * 4 + wave;
    float p = 0.0f, pm = -INFINITY;
    if (g < total) {
        int b    = g / MAX_BOXES;
        int slot = g - b * MAX_BOXES;
        if (slot < cnt[b]) {
            int cell = list[g];
            int ba = cell / HW;          // b*NUM_ANCHORS + a
            int hw = cell - ba * HW;     // gj*nW + gi
            const float* ptr = output + ((long)(ba * (5 + NUM_CLASSES) + 5)) * HW + hw;
            float v0 = ptr[(long)lane * HW];
            float v1 = (lane < NUM_CLASSES - 64) ? ptr[(long)(lane + 64) * HW] : -INFINITY;
            float mx = fmaxf(v0, v1);
            #pragma unroll
            for (int off = 32; off; off >>= 1) mx = fmaxf(mx, __shfl_xor(mx, off, 64));
            float e0 = expf(v0 - mx);
            float e1 = (lane < NUM_CLASSES - 64) ? expf(v1 - mx) : 0.0f;
            float s = e0 + e1;
            #pragma unroll
            for (int off = 32; off; off >>= 1) s += __shfl_xor(s, off, 64);
            int rq = *reqd;
            float lr = (rq < 64) ? __shfl(v0, rq, 64) : __shfl(v1, rq - 64, 64);
            p = expf(lr - mx) / s;
            pm = p;
        }
    }
    if (lane == 0) { sp[wave] = p; sm[wave] = pm; }
    __syncthreads();
    if (threadIdx.x == 0) {
        float ts = 0.0f, tm = -INFINITY;
        #pragma unroll
        for (int w = 0; w < 4; ++w) { ts += sp[w]; tm = fmaxf(tm, sm[w]); }
        psum[blockIdx.x] = ts;          // unconditional: every slot defined
        pmax[blockIdx.x] = tm;
    }
}

// Single block: tree-reduce the per-block partials + per-batch counts.
__global__ void __launch_bounds__(1024)
finalize(const int* __restrict__ cnt,
         const float* __restrict__ psum,
         const float* __restrict__ pmax,
         float* __restrict__ out,
         int nblocks, int nB) {
    __shared__ float ss[16];
    __shared__ float sx[16];
    __shared__ int   sc[16];
    int tid = threadIdx.x;
    float s = 0.0f, m = -INFINITY;
    int   c = 0;
    for (int i = tid; i < nblocks; i += 1024) { s += psum[i]; m = fmaxf(m, pmax[i]); }
    if (tid < nB) c = cnt[tid];
    #pragma unroll
    for (int off = 32; off; off >>= 1) {
        s += __shfl_xor(s, off, 64);
        m = fmaxf(m, __shfl_xor(m, off, 64));
        c += __shfl_xor(c, off, 64);
    }
    int lane = tid & 63, wv = tid >> 6;
    if (lane == 0) { ss[wv] = s; sx[wv] = m; sc[wv] = c; }
    __syncthreads();
    if (tid == 0) {
        float S = 0.0f, M = -INFINITY; int C = 0;
        #pragma unroll
        for (int i = 0; i < 16; ++i) { S += ss[i]; M = fmaxf(M, sx[i]); C += sc[i]; }
        out[0] = S / (float)C;
        out[1] = M;
    }
}

extern "C" void kernel_launch(void* const* d_in, const int* in_sizes, int n_in,
                              void* d_out, int out_size, void* d_ws, size_t ws_size,
                              hipStream_t stream) {
    const float* output = (const float*)d_in[0];
    const float* target = (const float*)d_in[1];
    const int*   reqd   = (const int*)d_in[2];
    float* out = (float*)d_out;

    int nB = in_sizes[1] / (MAX_BOXES * 5);                           // 64
    int HW = in_sizes[0] / (nB * (5 + NUM_CLASSES) * NUM_ANCHORS);    // 1444
    int nW = 1; while (nW * nW < HW) ++nW;                            // 38
    int nH = HW / nW;                                                 // 38

    int total   = nB * MAX_BOXES;                                     // 3200
    int rblocks = (total + 3) / 4;                                    // 800

    uint32_t* ws   = (uint32_t*)d_ws;
    int*      cnt  = (int*)ws;                                        // [nB]
    int*      list = (int*)(ws + nB);                                 // [total]
    float*    psum = (float*)(ws + nB + total);                       // [rblocks]
    float*    pmax = psum + rblocks;                                  // [rblocks]

    build_list<<<nB, 64, 0, stream>>>(target, cnt, list, nH, nW);

    reduce_list<<<rblocks, 256, 0, stream>>>(output, cnt, list, psum, pmax,
                                             reqd, HW, total);

    finalize<<<1, 1024, 0, stream>>>(cnt, psum, pmax, out, rblocks, nB);
}

// Round 5
// 199.312 us; speedup vs baseline: 1.2126x; 1.0075x over previous
//
#include <hip/hip_runtime.h>
#include <stdint.h>
#include <math.h>

#define NUM_ANCHORS 5
#define NUM_CLASSES 80
#define MAX_BOXES   50

// Two launches, zero atomics, zero workspace pre-init (ws is harness-poisoned
// every iteration, so nothing may be read before being written this iteration).
//
// fused kernel: one wave per (batch, slot). Each wave RECOMPUTES its batch's
// build (1KB target row, L2-hot; 50-shfl dedup) instead of reading a list a
// prior kernel produced — deletes the build_list launch and its dependency
// stall. Redundant recompute is free: it overlaps across 3200 concurrent
// waves (device capacity 8192).
//   psum/pmax/pcnt[block] written unconditionally -> no init, no atomics.
// finalize: single block tree-reduces 800 partials.
//
// History: last-block-done finalize (800x __threadfence + same-addr atomics)
// cost ~10us on gfx950 (cross-XCD fence traffic); single-block build cost
// ~16us (serialized latency). Both patterns intentionally absent.

__global__ void __launch_bounds__(256)
fused_region_loss(const float* __restrict__ output,
                  const float* __restrict__ target,
                  const int* __restrict__ reqd,
                  float* __restrict__ psum,
                  float* __restrict__ pmax,
                  int*   __restrict__ pcnt,
                  int nH, int nW, int HW, int total) {
#pragma clang fp contract(off)
    __shared__ float sp[4];
    __shared__ float sm[4];
    __shared__ int   sc[4];
    int lane = threadIdx.x & 63;
    int wave = threadIdx.x >> 6;
    int g = blockIdx.x * 4 + wave;
    float p = 0.0f, pm = -INFINITY;
    int   c = 0;

    if (g < total) {
        int b    = g / MAX_BOXES;
        int slot = g - b * MAX_BOXES;

        // ---- in-register build for batch b (lane = box index) ----
        const float* t = target + (long)b * MAX_BOXES * 5;
        float x = 1.0f, y = 0.0f, w = 0.0f, h = 0.0f;
        if (lane < MAX_BOXES) {
            x = t[lane * 5 + 1];
            y = t[lane * 5 + 2];
            w = t[lane * 5 + 3];
            h = t[lane * 5 + 4];
        }
        // valid = cumprod(x != 0): lanes strictly before the first zero box
        unsigned long long zb = __ballot(lane < MAX_BOXES && x == 0.0f);
        int first_zero = zb ? (__ffsll(zb) - 1) : MAX_BOXES;
        bool valid = lane < first_zero;   // implies lane < MAX_BOXES

        float gx = x * (float)nW;
        float gy = y * (float)nH;
        float gw = w * (float)nW;
        float gh = h * (float)nH;
        int gi = min(max((int)floorf(gx), 0), nW - 1);
        int gj = min(max((int)floorf(gy), 0), nH - 1);

        const float aw[NUM_ANCHORS] = {0.57273f, 1.87446f, 3.33843f, 7.88282f, 9.77052f};
        const float ah[NUM_ANCHORS] = {0.677385f, 2.06253f, 5.47434f, 3.52778f, 9.16828f};
        int best = 0; float bestiou = -1.0f;
        #pragma unroll
        for (int n = 0; n < NUM_ANCHORS; ++n) {
            float inter = fminf(gw, aw[n]) * fminf(gh, ah[n]);
            float uni   = gw * gh + aw[n] * ah[n] - inter;
            float iou   = inter / uni;
            if (iou > bestiou) { bestiou = iou; best = n; }  // first-max-wins
        }
        int flat = ((b * NUM_ANCHORS + best) * nH + gj) * nW + gi;

        // in-wave dedup: keep only the first occurrence among valid lanes
        unsigned long long vmask = __ballot(valid);
        bool dup = false;
        for (int j = 0; j < MAX_BOXES; ++j) {
            int fj = __shfl(flat, j, 64);
            dup |= (j < lane) && (((vmask >> j) & 1ull) != 0) && (fj == flat);
        }
        bool keep = valid && !dup;
        unsigned long long kmask = __ballot(keep);
        int cnt = (int)__popcll(kmask);
        if (slot == 0) c = cnt;          // slot-0 wave reports the batch count

        if (slot < cnt) {
            // broadcast the flat id whose dedup-rank == slot (exactly one lane)
            int rank = keep ? __popcll(kmask & ((1ull << lane) - 1ull)) : -1;
            int cell = (keep && rank == slot) ? flat : 0;
            #pragma unroll
            for (int off = 32; off; off >>= 1) cell |= __shfl_xor(cell, off, 64);

            // ---- 80-class softmax at this cell ----
            int ba = cell / HW;          // b*NUM_ANCHORS + a
            int hw = cell - ba * HW;     // gj*nW + gi
            const float* ptr = output + ((long)(ba * (5 + NUM_CLASSES) + 5)) * HW + hw;
            float v0 = ptr[(long)lane * HW];
            float v1 = (lane < NUM_CLASSES - 64) ? ptr[(long)(lane + 64) * HW] : -INFINITY;
            float mx = fmaxf(v0, v1);
            #pragma unroll
            for (int off = 32; off; off >>= 1) mx = fmaxf(mx, __shfl_xor(mx, off, 64));
            float e0 = expf(v0 - mx);
            float e1 = (lane < NUM_CLASSES - 64) ? expf(v1 - mx) : 0.0f;
            float s = e0 + e1;
            #pragma unroll
            for (int off = 32; off; off >>= 1) s += __shfl_xor(s, off, 64);
            int rq = *reqd;
            float lr = (rq < 64) ? __shfl(v0, rq, 64) : __shfl(v1, rq - 64, 64);
            p = expf(lr - mx) / s;
            pm = p;
        }
    }
    if (lane == 0) { sp[wave] = p; sm[wave] = pm; sc[wave] = c; }
    __syncthreads();
    if (threadIdx.x == 0) {
        float ts = 0.0f, tm = -INFINITY; int tc = 0;
        #pragma unroll
        for (int w = 0; w < 4; ++w) { ts += sp[w]; tm = fmaxf(tm, sm[w]); tc += sc[w]; }
        psum[blockIdx.x] = ts;           // unconditional: every slot defined
        pmax[blockIdx.x] = tm;
        pcnt[blockIdx.x] = tc;
    }
}

// Single block: tree-reduce the per-block partials.
__global__ void __launch_bounds__(1024)
finalize(const float* __restrict__ psum,
         const float* __restrict__ pmax,
         const int*   __restrict__ pcnt,
         float* __restrict__ out,
         int nblocks) {
    __shared__ float ss[16];
    __shared__ float sx[16];
    __shared__ int   sc[16];
    int tid = threadIdx.x;
    float s = 0.0f, m = -INFINITY;
    int   c = 0;
    for (int i = tid; i < nblocks; i += 1024) {
        s += psum[i];
        m = fmaxf(m, pmax[i]);
        c += pcnt[i];
    }
    #pragma unroll
    for (int off = 32; off; off >>= 1) {
        s += __shfl_xor(s, off, 64);
        m = fmaxf(m, __shfl_xor(m, off, 64));
        c += __shfl_xor(c, off, 64);
    }
    int lane = tid & 63, wv = tid >> 6;
    if (lane == 0) { ss[wv] = s; sx[wv] = m; sc[wv] = c; }
    __syncthreads();
    if (tid == 0) {
        float S = 0.0f, M = -INFINITY; int C = 0;
        #pragma unroll
        for (int i = 0; i < 16; ++i) { S += ss[i]; M = fmaxf(M, sx[i]); C += sc[i]; }
        out[0] = S / (float)C;
        out[1] = M;
    }
}

extern "C" void kernel_launch(void* const* d_in, const int* in_sizes, int n_in,
                              void* d_out, int out_size, void* d_ws, size_t ws_size,
                              hipStream_t stream) {
    const float* output = (const float*)d_in[0];
    const float* target = (const float*)d_in[1];
    const int*   reqd   = (const int*)d_in[2];
    float* out = (float*)d_out;

    int nB = in_sizes[1] / (MAX_BOXES * 5);                           // 64
    int HW = in_sizes[0] / (nB * (5 + NUM_CLASSES) * NUM_ANCHORS);    // 1444
    int nW = 1; while (nW * nW < HW) ++nW;                            // 38
    int nH = HW / nW;                                                 // 38

    int total   = nB * MAX_BOXES;                                     // 3200
    int rblocks = (total + 3) / 4;                                    // 800

    uint32_t* ws   = (uint32_t*)d_ws;
    float*    psum = (float*)ws;                                      // [rblocks]
    float*    pmax = psum + rblocks;                                  // [rblocks]
    int*      pcnt = (int*)(pmax + rblocks);                          // [rblocks]

    fused_region_loss<<<rblocks, 256, 0, stream>>>(output, target, reqd,
                                                   psum, pmax, pcnt,
                                                   nH, nW, HW, total);

    finalize<<<1, 1024, 0, stream>>>(psum, pmax, pcnt, out, rblocks);
}